// Round 4
// baseline (242.544 us; speedup 1.0000x reference)
//
#include <hip/hip_runtime.h>

// SynthesisStage: modulated conv2d w/ adaptive kernel selection.
// B=8, Ci=Co=256, H=W=128, K=3, N=4.
// v4: one-barrier-per-phase pipeline. Phase=(dh,kb,tap). Al tri-buffered
// (global_load_lds issued 2 phases ahead, counted vmcnt, never drain-0);
// XR double-buffered per (dh,kb) group, reg-staged x packed 2 phases after
// issue. setprio around MFMA cluster. cot-paired XCD dispatch for x L2 reuse.

typedef __attribute__((ext_vector_type(4))) float f32x4;
typedef __attribute__((ext_vector_type(8))) short s16x8;
typedef __attribute__((ext_vector_type(4))) unsigned int u32x4;

#define NB   8
#define NCI  256
#define NCO  256
#define NHW  128
#define NKER 4

__device__ __forceinline__ unsigned short f2bf(float f) {
  unsigned int u = __builtin_bit_cast(unsigned int, f);
  u += 0x7FFFu + ((u >> 16) & 1u);          // round-to-nearest-even
  return (unsigned short)(u >> 16);
}

__device__ __forceinline__ void gl_lds16(const void* g, void* l) {
  __builtin_amdgcn_global_load_lds(
      (const __attribute__((address_space(1))) void*)(unsigned long long)(uintptr_t)g,
      (__attribute__((address_space(3))) void*)(unsigned int)(uintptr_t)l,
      16, 0, 0);
}

// ---------------------------------------------------------------------------
// Kernel 1: modulated+demodulated weights -> bf16, PRE-SWIZZLED TILE LAYOUT.
// Tile T = ((b*9+tap)*2 + cot)*4 + kb is a 16KB LDS image: 128 rows (co) x
// 128B, value for (co,ci) at byte (co&127)*128 + ((2*(ci&63)) ^ ((co&7)<<4)).
// ---------------------------------------------------------------------------
__global__ __launch_bounds__(256) void prep_k(
    const float* __restrict__ weight,    // [N][Co][Ci][3][3]
    const float* __restrict__ styles,    // [B][Ci]
    const float* __restrict__ selector,  // [B][N]
    unsigned short* __restrict__ wmod)   // tiled-swizzled, 9.44 MB
{
  int bid = blockIdx.x;
  int b = bid >> 8, co = bid & 255;
  int ci = threadIdx.x;

  float sel[NKER];
#pragma unroll
  for (int n = 0; n < NKER; ++n) sel[n] = selector[b * NKER + n];

  float a[9];
#pragma unroll
  for (int j = 0; j < 9; ++j) a[j] = 0.f;
#pragma unroll
  for (int n = 0; n < NKER; ++n) {
    const float* wp = weight + (size_t)((n * NCO + co) * NCI + ci) * 9;
    float s = sel[n];
#pragma unroll
    for (int j = 0; j < 9; ++j) a[j] += s * wp[j];
  }
  float st = styles[b * NCI + ci];
  float ss = 0.f;
#pragma unroll
  for (int j = 0; j < 9; ++j) { a[j] *= st; ss += a[j] * a[j]; }

  for (int off = 32; off; off >>= 1) ss += __shfl_down(ss, off, 64);
  __shared__ float red[4];
  int wid = threadIdx.x >> 6, lane = threadIdx.x & 63;
  if (lane == 0) red[wid] = ss;
  __syncthreads();
  float tot = red[0] + red[1] + red[2] + red[3];
  float d = rsqrtf(tot + 1e-8f);

  int cot = co >> 7, kb = ci >> 6;
  int pb = ((ci & 63) << 1) ^ ((co & 7) << 4);    // swizzled byte in row
#pragma unroll
  for (int j = 0; j < 9; ++j) {
    size_t T = (size_t)(((b * 9 + j) * 2 + cot) * 4 + kb);
    wmod[(T << 13) + ((co & 127) << 6) + (pb >> 1)] = f2bf(a[j] * d);
  }
}

// ---------------------------------------------------------------------------
// Kernel 2: implicit-GEMM conv, 1-barrier-per-phase pipeline.
// block = (b, h, cot); 256 thr = 4 waves (2x2 grid, 64co x 64px each).
// ---------------------------------------------------------------------------
__global__ __launch_bounds__(256, 2) void conv_k(
    const float* __restrict__ x,              // [B][Ci][H][W] f32
    const unsigned short* __restrict__ wg,    // tiled-swizzled wmod
    const float* __restrict__ noise,          // [B][Co][H][W]
    float* __restrict__ out)                  // [B][Co][H][W]
{
  extern __shared__ __align__(16) char smem[];
  char* AlB = smem;                  // 3 x 16KB tri-buffer (weights, one tap)
  char* XRB = smem + 3 * 16384;      // 2 x 16KB dbuf (x row, one kb slice)

  // dispatch: XCD k (orig%8) owns sample b=k; (h, cot) pairs adjacent so the
  // two cot blocks for one (b,h) share x rows via L1/L2.
  int orig = blockIdx.x;
  int b = orig & 7;
  int j = orig >> 3;                 // 0..255
  int h = j >> 1;
  int cot = j & 1;
  int co0 = cot << 7;

  int t = threadIdx.x;
  int lane = t & 63;
  int wid = t >> 6;
  int wr = wid >> 1, wc = wid & 1;
  int ll = lane & 15;

  int dh0 = (h == 0) ? 1 : 0;
  int nseg = 3 - (h == 0) - (h == 127);
  int NG = nseg << 2;                // groups = (dh, kb)

  f32x4 acc[4][4];
#pragma unroll
  for (int m = 0; m < 4; ++m)
#pragma unroll
    for (int n = 0; n < 4; ++n) acc[m][n] = (f32x4){0.f, 0.f, 0.f, 0.f};

  // XR staging: thread owns ci-pair (bc,bc+1) x 16 w
  int bc = (t & 31) * 2;
  int bwg = t >> 5;

  f32x4 xna[4], xnb[4];              // reg-staged x (8 loads in flight)

  auto issueX = [&](int g) {
    int gc = g < NG ? g : NG - 1;
    int dh = dh0 + (gc >> 2);
    int kb = gc & 3;
    int hy = h + dh - 1;
    const f32x4* x40 = (const f32x4*)(x +
        ((size_t)(b * NCI + kb * 64 + bc) * NHW + hy) * NHW) + bwg * 4;
    const f32x4* x41 = x40 + (NHW * NHW / 4);
#pragma unroll
    for (int jj = 0; jj < 4; ++jj) { xna[jj] = x40[jj]; xnb[jj] = x41[jj]; }
  };

  // stage one 16KB weight tile (group gg, tap) into Al buffer `buf`
  auto issueA = [&](int gg, int tap, int buf) {
    int gc = gg < NG ? gg : NG - 1;
    int dh = dh0 + (gc >> 2);
    int kb = gc & 3;
    size_t T = (size_t)(((b * 9 + dh * 3 + tap) * 2 + cot) * 4 + kb);
    const char* src = (const char*)wg + (T << 14);
    char* dst = AlB + buf * 16384;
#pragma unroll
    for (int i = 0; i < 4; ++i) {
      int c = wid * 4 + i;
      gl_lds16(src + c * 1024 + lane * 16, dst + c * 1024 + lane * 16);
    }
  };

  auto packXR = [&](int g) {
    char* dst = XRB + (g & 1) * 16384;
#pragma unroll
    for (int jj = 0; jj < 4; ++jj) {
#pragma unroll
      for (int e = 0; e < 4; ++e) {
        int w = bwg * 16 + jj * 4 + e;
        unsigned int pk = ((unsigned int)f2bf(xnb[jj][e]) << 16) | f2bf(xna[jj][e]);
        *(unsigned int*)(dst + w * 128 + ((bc * 2) ^ ((w & 7) << 4))) = pk;
      }
    }
  };

  auto compute = [&](int dw, int albuf, int xrbuf) {
    const char* Ab = AlB + albuf * 16384;
    const char* Xb = XRB + xrbuf * 16384;
    __builtin_amdgcn_s_setprio(1);
#pragma unroll
    for (int ks = 0; ks < 2; ++ks) {
      int cib = ks * 64 + ((lane >> 4) << 4);
      s16x8 af[4], bf[4];
#pragma unroll
      for (int m = 0; m < 4; ++m) {
        int row = wr * 64 + m * 16 + ll;
        af[m] = *(const s16x8*)(Ab + row * 128 + (cib ^ ((row & 7) << 4)));
      }
#pragma unroll
      for (int n = 0; n < 4; ++n) {
        int wn = wc * 64 + n * 16 + ll + dw - 1;
        if ((dw == 0 && n == 0) || (dw == 2 && n == 3)) {
          int wx = wn < 0 ? 0 : (wn > 127 ? 127 : wn);
          s16x8 bv = *(const s16x8*)(Xb + wx * 128 + (cib ^ ((wx & 7) << 4)));
          if (wn != wx) { s16x8 z = {0, 0, 0, 0, 0, 0, 0, 0}; bv = z; }
          bf[n] = bv;
        } else {
          bf[n] = *(const s16x8*)(Xb + wn * 128 + (cib ^ ((wn & 7) << 4)));
        }
      }
#pragma unroll
      for (int m = 0; m < 4; ++m)
#pragma unroll
        for (int n = 0; n < 4; ++n)
          acc[m][n] = __builtin_amdgcn_mfma_f32_16x16x32_bf16(
              af[m], bf[n], acc[m][n], 0, 0, 0);
    }
    __builtin_amdgcn_s_setprio(0);
  };

// one barrier per phase; N = allowed in-flight VMEM after the wait
#define PHASE_WAIT(N)                                                   \
  asm volatile("s_waitcnt vmcnt(" #N ") lgkmcnt(0)" ::: "memory");      \
  __builtin_amdgcn_s_barrier();                                         \
  __builtin_amdgcn_sched_barrier(0);

  // ---- prologue: x(0) [8 loads], Al(g0,t0)->buf0, Al(g0,t1)->buf1 ----
  issueX(0);
  issueA(0, 0, 0);
  issueA(0, 1, 1);
  asm volatile("s_waitcnt vmcnt(8)" ::: "memory");   // drain x(0); keep 8 gloads
  packXR(0);

#pragma unroll 1
  for (int g = 0; g < NG; ++g) {
    int xrb = g & 1;
    int dh = dh0 + (g >> 2);
    (void)dh;
    // ---- tap 0 ---- outstanding before wait: Al(p)4 + Al(p+1)4
    PHASE_WAIT(4)
    issueA(g, 2, 2);                 // tile (g, tap2) -> buf2
    issueX(g + 1);                   // 8 x loads for next group's XR
    compute(0, 0, xrb);
    // ---- tap 1 ---- outstanding: Al(p)4 [oldest], Al(p+1)4, x8
    PHASE_WAIT(12)
    issueA(g + 1, 0, 0);             // tile (g+1, tap0) -> buf0
    compute(1, 1, xrb);
    // ---- tap 2 ---- outstanding: Al(p)4 [oldest], x8, Al(p+1)4
    PHASE_WAIT(12)
    issueA(g + 1, 1, 1);             // tile (g+1, tap1) -> buf1
    asm volatile("s_waitcnt vmcnt(8)" ::: "memory");  // drain x regs only
    packXR(g + 1);
    compute(2, 2, xrb);
  }

  // epilogue: D[row=(lane>>4)*4+j][col=lane&15], fused noise add
  int pc = ll;
  int pr4 = (lane >> 4) * 4;
#pragma unroll
  for (int m = 0; m < 4; ++m) {
#pragma unroll
    for (int n = 0; n < 4; ++n) {
      int px = wc * 64 + n * 16 + pc;
#pragma unroll
      for (int jj = 0; jj < 4; ++jj) {
        int co = co0 + wr * 64 + m * 16 + pr4 + jj;
        size_t idx = ((size_t)(b * NCO + co) * NHW + h) * NHW + px;
        out[idx] = acc[m][n][jj] + noise[idx];
      }
    }
  }
}

// ---------------------------------------------------------------------------
extern "C" void kernel_launch(void* const* d_in, const int* in_sizes, int n_in,
                              void* d_out, int out_size, void* d_ws, size_t ws_size,
                              hipStream_t stream) {
  const float* x        = (const float*)d_in[0];
  const float* weight   = (const float*)d_in[1];
  const float* styles   = (const float*)d_in[2];
  const float* selector = (const float*)d_in[3];
  const float* noise    = (const float*)d_in[4];
  float* out = (float*)d_out;

  // workspace: ONLY wmod (tiled-swizzled) = 9,437,184 bytes
  unsigned short* wmod = (unsigned short*)d_ws;

  hipLaunchKernelGGL(prep_k, dim3(NB * NCO), dim3(256), 0, stream,
                     weight, styles, selector, wmod);
  hipLaunchKernelGGL(conv_k, dim3(NB * 2 * NHW), dim3(256), 80 * 1024, stream,
                     x, wmod, noise, out);
}

// Round 5
// 189.073 us; speedup vs baseline: 1.2828x; 1.2828x over previous
//
#include <hip/hip_runtime.h>

// SynthesisStage: modulated conv2d w/ adaptive kernel selection.
// B=8, Ci=Co=256, H=W=128, K=3, N=4.
// v5: 8-phase-template port. Block=(b,h): 256co x 128px, 4 waves of
// 64co x 128px. 72 K-tiles of 32ci (tap-major). Al tri-buffer via
// global_load_lds (pre-swizzled tiles, issued 2 ahead), XR dbuf packed
// from reg-staged x (issued 2 sub-phases ahead). One sub-phase per tile:
// reads -> issues -> bar -> lgkm0 -> setprio/MFMA -> counted vmcnt -> bar.

typedef __attribute__((ext_vector_type(4))) float f32x4;
typedef __attribute__((ext_vector_type(8))) short s16x8;

#define NB   8
#define NCI  256
#define NCO  256
#define NHW  128
#define NKER 4

#define SB0 __builtin_amdgcn_sched_barrier(0)
#define BAR __builtin_amdgcn_s_barrier()
#define WAITV(N) asm volatile("s_waitcnt vmcnt(" #N ")" ::: "memory")
#define WAITL0   asm volatile("s_waitcnt lgkmcnt(0)" ::: "memory")

__device__ __forceinline__ unsigned short f2bf(float f) {
  unsigned int u = __builtin_bit_cast(unsigned int, f);
  u += 0x7FFFu + ((u >> 16) & 1u);          // round-to-nearest-even
  return (unsigned short)(u >> 16);
}

__device__ __forceinline__ void gl_lds16(const void* g, void* l) {
  __builtin_amdgcn_global_load_lds(
      (const __attribute__((address_space(1))) void*)(unsigned long long)(uintptr_t)g,
      (__attribute__((address_space(3))) void*)(unsigned int)(uintptr_t)l,
      16, 0, 0);
}

// ---------------------------------------------------------------------------
// Kernel 1: modulated+demodulated weights -> bf16 pre-swizzled 16KB tiles.
// Tile T = (b*9+tap)*8 + kb holds 256co x 32ci as 128 rows x 128B:
// (co,ci5) at row=co>>1, byte=((((co&1)*4+(ci5>>3)) ^ (row&7))<<4)+(ci5&7)*2
// ---------------------------------------------------------------------------
__global__ __launch_bounds__(256) void prep_k(
    const float* __restrict__ weight,    // [N][Co][Ci][3][3]
    const float* __restrict__ styles,    // [B][Ci]
    const float* __restrict__ selector,  // [B][N]
    unsigned short* __restrict__ wmod)   // tiled-swizzled, 9.44 MB
{
  int bid = blockIdx.x;
  int b = bid >> 8, co = bid & 255;
  int ci = threadIdx.x;

  float sel[NKER];
#pragma unroll
  for (int n = 0; n < NKER; ++n) sel[n] = selector[b * NKER + n];

  float a[9];
#pragma unroll
  for (int j = 0; j < 9; ++j) a[j] = 0.f;
#pragma unroll
  for (int n = 0; n < NKER; ++n) {
    const float* wp = weight + (size_t)((n * NCO + co) * NCI + ci) * 9;
    float s = sel[n];
#pragma unroll
    for (int j = 0; j < 9; ++j) a[j] += s * wp[j];
  }
  float st = styles[b * NCI + ci];
  float ss = 0.f;
#pragma unroll
  for (int j = 0; j < 9; ++j) { a[j] *= st; ss += a[j] * a[j]; }

  for (int off = 32; off; off >>= 1) ss += __shfl_down(ss, off, 64);
  __shared__ float red[4];
  int wid = threadIdx.x >> 6, lane = threadIdx.x & 63;
  if (lane == 0) red[wid] = ss;
  __syncthreads();
  float tot = red[0] + red[1] + red[2] + red[3];
  float d = rsqrtf(tot + 1e-8f);

  int kb = ci >> 5, ci5 = ci & 31;
  int row = co >> 1;
  int slot = (((co & 1) << 2) + (ci5 >> 3)) ^ (row & 7);
  int boff = (slot << 4) + ((ci5 & 7) << 1);     // byte in 128B row
#pragma unroll
  for (int j = 0; j < 9; ++j) {
    size_t T = (size_t)((b * 9 + j) * 8 + kb);
    wmod[(T << 13) + (row << 6) + (boff >> 1)] = f2bf(a[j] * d);
  }
}

// ---------------------------------------------------------------------------
// Kernel 2: implicit-GEMM conv, sub-phase pipeline.
// ---------------------------------------------------------------------------
__global__ __launch_bounds__(256, 2) void conv_k(
    const float* __restrict__ x,              // [B][Ci][H][W] f32
    const unsigned short* __restrict__ wg,    // pre-swizzled wmod tiles
    const float* __restrict__ noise,          // [B][Co][H][W]
    float* __restrict__ out)                  // [B][Co][H][W]
{
  extern __shared__ __align__(16) char smem[];
  char* AlB = smem;                  // 3 x 16KB tri-buffer (one K-tile each)
  char* XRs = smem + 3 * 16384;      // 2 x 8KB dbuf (x slice 128w x 32ci)

  int orig = blockIdx.x;             // 1024 blocks
  int b = orig & 7;                  // XCD-resident sample
  int h = orig >> 3;

  int t = threadIdx.x;
  int lane = t & 63;
  int wid = t >> 6;                  // wave id 0..3 -> co base
  int cow = wid << 6;
  int ll = lane & 15;
  int ks = lane >> 4;                // k-slice 0..3 (8 ci each)

  int dh0 = (h == 0) ? 1 : 0;
  int nseg = 3 - (h == 0) - (h == 127);
  int NG = nseg << 3;                // groups = (seg, kb)
  int NT = NG * 3;                   // tiles (tap-minor)

  f32x4 acc[4][8];
#pragma unroll
  for (int m = 0; m < 4; ++m)
#pragma unroll
    for (int n = 0; n < 8; ++n) acc[m][n] = (f32x4){0.f, 0.f, 0.f, 0.f};

  // x staging: thread owns ci-pair (c,c+1) x 8 w's (w = (t&15) + 16*j)
  int c = ((t >> 4) & 15) * 2;       // 0..30, (c>>3) == wave id
  int wi = t & 15;
  float xlo[8], xhi[8];

  auto issueX = [&](int g) {
    int gc = g < NG ? g : NG - 1;
    int dh = dh0 + (gc >> 3);
    int kb = gc & 7;
    int hy = h + dh - 1;
    const float* base = x + ((size_t)(b * NCI + kb * 32 + c) * NHW + hy) * NHW + wi;
#pragma unroll
    for (int j2 = 0; j2 < 8; ++j2) {
      xlo[j2] = base[j2 * 16];
      xhi[j2] = base[NHW * NHW + j2 * 16];
    }
  };

  auto issueA = [&](int tauc, int buf) {     // tauc = clamped tile index
    int gg = tauc / 3;
    int tap = tauc - gg * 3;
    int dh = dh0 + (gg >> 3);
    int kb = gg & 7;
    const char* src = (const char*)wg +
        ((size_t)((b * 9 + dh * 3 + tap) * 8 + kb) << 14);
    char* dst = AlB + buf * 16384;
#pragma unroll
    for (int i = 0; i < 4; ++i) {
      int ch = wid * 4 + i;
      gl_lds16(src + ch * 1024 + lane * 16, dst + ch * 1024 + lane * 16);
    }
  };

  auto packXR = [&](int g) {
    char* dstb = XRs + (g & 1) * 8192;
    int slot = (((wi & 1) << 2) + (c >> 3)) ^ ((wi >> 1) & 7);
    char* p0 = dstb + (wi >> 1) * 128 + (slot << 4) + ((c & 7) << 1);
#pragma unroll
    for (int j2 = 0; j2 < 8; ++j2) {
      unsigned int pk = ((unsigned)f2bf(xhi[j2]) << 16) | f2bf(xlo[j2]);
      *(unsigned int*)(p0 + j2 * 1024) = pk;  // row = 8*j2 + (wi>>1)
    }
  };

  auto readA = [&](int buf, s16x8* af) {
    const char* Ab = AlB + buf * 16384;
#pragma unroll
    for (int m = 0; m < 4; ++m) {
      int co = cow + m * 16 + ll;
      int row = co >> 1;
      int slot = (((co & 1) << 2) + ks) ^ (row & 7);
      af[m] = *(const s16x8*)(Ab + row * 128 + (slot << 4));
    }
  };
  auto readB = [&](int xrb, int dw, s16x8* bf) {
    const char* Xb = XRs + xrb * 8192;
#pragma unroll
    for (int n = 0; n < 8; ++n) {
      int wn = n * 16 + ll + dw - 1;
      if ((dw == 0 && n == 0) || (dw == 2 && n == 7)) {
        int wx = wn < 0 ? 0 : (wn > 127 ? 127 : wn);
        int row = wx >> 1;
        int slot = (((wx & 1) << 2) + ks) ^ (row & 7);
        s16x8 bv = *(const s16x8*)(Xb + row * 128 + (slot << 4));
        if (wn != wx) { s16x8 z = {0, 0, 0, 0, 0, 0, 0, 0}; bv = z; }
        bf[n] = bv;
      } else {
        int row = wn >> 1;
        int slot = (((wn & 1) << 2) + ks) ^ (row & 7);
        bf[n] = *(const s16x8*)(Xb + row * 128 + (slot << 4));
      }
    }
  };
  auto mfma32 = [&](s16x8* af, s16x8* bf) {
    __builtin_amdgcn_s_setprio(1);
#pragma unroll
    for (int m = 0; m < 4; ++m)
#pragma unroll
      for (int n = 0; n < 8; ++n)
        acc[m][n] = __builtin_amdgcn_mfma_f32_16x16x32_bf16(
            af[m], bf[n], acc[m][n], 0, 0, 0);
    __builtin_amdgcn_s_setprio(0);
  };

  // ---- prologue: x(0)[16], A(0)->buf0, A(1)->buf1 ----
  issueX(0); SB0;
  issueA(0, 0); SB0;
  issueA(1, 1); SB0;
  WAITV(8); SB0;                     // drain x(0); keep A0,A1 (8)
  packXR(0);
  WAITV(4); SB0;                     // drain A0; keep A1
  WAITL0; SB0;
  BAR; SB0;

#pragma unroll 1
  for (int g = 0; g < NG; ++g) {
    int xrb = g & 1;
    int tau = g * 3;
    // ---- tile t0 (buf0): issue A(tau+2)->buf2, x(g+1) ----
    {
      s16x8 af[4], bf[8];
      readA(0, af); readB(xrb, 0, bf);
      issueA(tau + 2, 2); SB0;       // tau+2 <= NT-1 always
      issueX(g + 1); SB0;
      BAR; WAITL0; SB0;
      mfma32(af, bf);
      WAITV(20); SB0;                // drain A(t1); keep A(t2)4 + x16
      BAR; SB0;
    }
    // ---- tile t1 (buf1): issue A(g+1,t0)->buf0 ----
    {
      s16x8 af[4], bf[8];
      readA(1, af); readB(xrb, 1, bf);
      int tc = tau + 3; if (tc > NT - 1) tc = NT - 1;
      issueA(tc, 0); SB0;
      BAR; WAITL0; SB0;
      mfma32(af, bf);
      WAITV(20); SB0;                // drain A(t2); keep x16 + A(g+1,t0)4
      BAR; SB0;
    }
    // ---- tile t2 (buf2): issue A(g+1,t1)->buf1; pack XR(g+1) ----
    {
      s16x8 af[4], bf[8];
      readA(2, af); readB(xrb, 2, bf);
      int tc = tau + 4; if (tc > NT - 1) tc = NT - 1;
      issueA(tc, 1); SB0;
      WAITV(4); SB0;                 // drain x16 + A(g+1,t0); keep A(g+1,t1)
      packXR(g + 1);
      BAR; WAITL0; SB0;              // lgkm covers own reads + pack writes
      mfma32(af, bf);
      BAR; SB0;
    }
  }

  // epilogue: D[row=ks*4+j][col=ll], fused noise add
  int pr4 = ks * 4;
#pragma unroll
  for (int m = 0; m < 4; ++m) {
#pragma unroll
    for (int n = 0; n < 8; ++n) {
      int px = n * 16 + ll;
#pragma unroll
      for (int j = 0; j < 4; ++j) {
        int co = cow + m * 16 + pr4 + j;
        size_t idx = ((size_t)(b * NCO + co) * NHW + h) * NHW + px;
        out[idx] = acc[m][n][j] + noise[idx];
      }
    }
  }
}

// ---------------------------------------------------------------------------
extern "C" void kernel_launch(void* const* d_in, const int* in_sizes, int n_in,
                              void* d_out, int out_size, void* d_ws, size_t ws_size,
                              hipStream_t stream) {
  const float* x        = (const float*)d_in[0];
  const float* weight   = (const float*)d_in[1];
  const float* styles   = (const float*)d_in[2];
  const float* selector = (const float*)d_in[3];
  const float* noise    = (const float*)d_in[4];
  float* out = (float*)d_out;

  // workspace: ONLY wmod (pre-swizzled tiles) = 9,437,184 bytes
  unsigned short* wmod = (unsigned short*)d_ws;

  hipLaunchKernelGGL(prep_k, dim3(NB * NCO), dim3(256), 0, stream,
                     weight, styles, selector, wmod);
  hipLaunchKernelGGL(conv_k, dim3(NB * NHW), dim3(256), 64 * 1024, stream,
                     x, wmod, noise, out);
}